// Round 1
// 1064.018 us; speedup vs baseline: 1.5889x; 1.5889x over previous
//
#include <hip/hip_runtime.h>
#include <hip/hip_fp16.h>

// FFT cross-correlation via overlap-save, fp16 spectra, ws-size-adaptive chunking.
// signal (32,128,8192) f32, weight (128,128,2048) f32, bias (128) f32
// out[b,o,t] = sum_i sum_k s_pad[b,i,t+k]*w[o,i,k] + bias[o], t in [0,8192]
// Blocks of 4096 (hop 2048, 4 per batch row); real FFT via packed complex
// Stockham FFT of M=2048 (natural order). Spectra stored as __half2 (4B/bin).
// Round 1: einsum rewritten as MFMA complex GEMM (v_mfma_f32_16x16x32_f16).

#define THREADS 256
#define FP 2056   // padded bins per row (valid f=0..2048); row = 8224 B, 16B-aligned

struct alignas(16) H2x4 { __half2 h[4]; };

typedef _Float16 f16x8 __attribute__((ext_vector_type(8)));
typedef float f32x4 __attribute__((ext_vector_type(4)));

__device__ __forceinline__ float2 f2(float x, float y){ return make_float2(x, y); }
__device__ __forceinline__ __half2 pack2(float x, float y){ return __floats2half2_rn(x, y); }
__device__ __forceinline__ float2 unpack2(__half2 h){
  return make_float2(__low2float(h), __high2float(h));
}

// In-LDS Stockham radix-2 complex FFT, size 2048, 256 threads.
// sign=-1 fwd, +1 inv (unscaled). Twiddles via v_sin/v_cos (revolutions).
__device__ float2* fft2048(float2* A, float2* B, int tid, float sign){
  float2* src = A; float2* dst = B;
  #pragma unroll 1
  for (int s = 0; s < 11; ++s){
    const int Ls = 1 << s;
    const float crev = sign * 0.5f / (float)Ls;  // rev per p: angle = sign*pi*p/Ls
    __syncthreads();
    #pragma unroll
    for (int r = 0; r < 4; ++r){
      int j = tid + (r << 8);
      int p = j & (Ls - 1);
      int q = j >> s;
      float rev = crev * (float)p;
      float sw = __builtin_amdgcn_sinf(rev);
      float cw = __builtin_amdgcn_cosf(rev);
      float2 a = src[j];
      float2 b = src[j + 1024];
      float tr = b.x*cw - b.y*sw;
      float ti = b.x*sw + b.y*cw;
      int o0 = (q << (s+1)) + p;
      dst[o0]      = f2(a.x + tr, a.y + ti);
      dst[o0 + Ls] = f2(a.x - tr, a.y - ti);
    }
    float2* t = src; src = dst; dst = t;
  }
  __syncthreads();
  return src;
}

// Packed spectrum Z (M=2048) -> rfft bins X[0..2048] of length-4096 real seq,
// stored fp16 to global row; zero the pad bins 2049..2055.
__device__ void unpack_store(const float2* Z, __half2* out, int tid){
  for (int k = tid; k < 2048; k += THREADS){
    float2 zk = Z[k];
    float2 zm = Z[(2048 - k) & 2047];
    float ar =  0.5f*(zk.x + zm.x);
    float ai =  0.5f*(zk.y - zm.y);
    float br =  0.5f*(zk.y + zm.y);
    float bi = -0.5f*(zk.x - zm.x);
    float rev = -(float)k * (1.0f/4096.0f);   // W_4096^k
    float sw = __builtin_amdgcn_sinf(rev);
    float cw = __builtin_amdgcn_cosf(rev);
    out[k] = pack2(ar + cw*br - sw*bi, ai + cw*bi + sw*br);
  }
  if (tid == 0){
    float2 z0 = Z[0];
    out[2048] = pack2(z0.x - z0.y, 0.0f);     // Nyquist
  }
  if (tid >= 1 && tid < 8) out[2048 + tid] = pack2(0.0f, 0.0f);
}

// Weight FFT for o-chunk: local row = o_local*128+i, global o = o_base+o_local.
__global__ __launch_bounds__(THREADS) void kfft_w(const float* __restrict__ w,
                                                  __half2* __restrict__ Wc, int o_base){
  __shared__ float2 A[2048]; __shared__ float2 B[2048];
  int lr = blockIdx.x;
  int grow = (o_base + (lr >> 7)) * 128 + (lr & 127);
  const float2* wv = (const float2*)(w + (size_t)grow * 2048);
  for (int n = threadIdx.x; n < 2048; n += THREADS)
    A[n] = (n < 1024) ? wv[n] : f2(0.f, 0.f);
  float2* Z = fft2048(A, B, threadIdx.x, -1.0f);
  unpack_store(Z, Wc + (size_t)lr * FP, threadIdx.x);
}

// Signal block FFT for bb-chunk: local row = bb_local*128+i, bb = bb_base+bb_local,
// bb = b*4+blk. x[m]=s_pad[blk*2048+m]; float2 idx q = n + blk*1024 - 512.
__global__ __launch_bounds__(THREADS) void kfft_s(const float* __restrict__ sig,
                                                  __half2* __restrict__ Xc, int bb_base){
  __shared__ float2 A[2048]; __shared__ float2 B[2048];
  int lr = blockIdx.x;
  int bb = bb_base + (lr >> 7), i = lr & 127;
  int b = bb >> 2, blk = bb & 3;
  const float2* sv = (const float2*)(sig + (size_t)(b*128 + i) * 8192);
  for (int n = threadIdx.x; n < 2048; n += THREADS){
    int q = n + blk*1024 - 512;
    A[n] = (q >= 0 && q < 4096) ? sv[q] : f2(0.f, 0.f);
  }
  float2* Z = fft2048(A, B, threadIdx.x, -1.0f);
  unpack_store(Z, Xc + (size_t)lr * FP, threadIdx.x);
}

// ---------------------------------------------------------------------------
// MFMA complex einsum: Y[bb,o,f] = sum_i X[bb,i,f]*conj(W[o,i,f]).
// Block tile: 64 bb x 64 o x 4 f-bins; K=i streamed in 4 chunks of 32.
// Planar LDS staging (Xr/Xi, Wr/Wi de-interleaved), XOR-swizzled rows.
// Yr = Xr*Wr + Xi*Wi ; Yi = Xi*Wr + (-Xr)*Wi  (2 accs, 4 MFMA per tile/chunk).
// Grid: x = nbbBlk*noBlk*(FP/4), XCD-bijective swizzle so each XCD sweeps a
// contiguous f-range of one spatial tile (L2 line reuse for 16B strided rows).
// ---------------------------------------------------------------------------
__global__ __launch_bounds__(THREADS, 2) void kceinsum(
    const __half2* __restrict__ Xc, const __half2* __restrict__ Wc,
    __half2* __restrict__ Yc, int nbbBlk, int OC)
{
  __shared__ uint4 smem[4160];                 // 66560 B: staging 64KB / epi 66.56KB
  char* sb = (char*)smem;
  const int nFB = FP/4;                        // 514
  int total = gridDim.x;
  int wg = blockIdx.x;
  int w = ((total & 7) == 0) ? ((wg & 7) * (total >> 3) + (wg >> 3)) : wg;
  int x = w / nFB;                             // spatial tile (x-major => f-contig per XCD)
  int y = w - x * nFB;                         // f block
  const int bb0 = (x % nbbBlk) * 64;
  const int o0  = (x / nbbBlk) * 64;
  const int f0  = y * 4;

  const int tid = threadIdx.x;
  const int wave = tid >> 6, lane = tid & 63;
  const int wm = wave & 1, wn = wave >> 1;     // 2x2 wave grid over 64x64 tile
  const int l15 = lane & 15, l4 = lane >> 4;

  const f32x4 zv = {0.f, 0.f, 0.f, 0.f};
  f32x4 accR[2][2][4], accI[2][2][4];
  #pragma unroll
  for (int mt = 0; mt < 2; ++mt)
    #pragma unroll
    for (int nt = 0; nt < 2; ++nt)
      #pragma unroll
      for (int c = 0; c < 4; ++c){ accR[mt][nt][c] = zv; accI[mt][nt][c] = zv; }

  for (int ic = 0; ic < 4; ++ic){
    __syncthreads();
    // ---- stage: each thread loads 4 (row, i-pair) for A and B: 16B per row ----
    uint4 va0[4], va1[4], vb0[4], vb1[4];
    #pragma unroll
    for (int rep = 0; rep < 4; ++rep){
      int q = tid + rep*THREADS;               // pair id 0..1023
      int r0 = q >> 4;                         // bb / o row 0..63
      int ip = (q & 15) << 1;                  // i within chunk: 0,2..30
      const __half2* pA = Xc + ((size_t)(bb0 + r0)*128 + ic*32 + ip)*FP + f0;
      va0[rep] = *(const uint4*)pA;
      va1[rep] = *(const uint4*)(pA + FP);
      const __half2* pB = Wc + ((size_t)(o0 + r0)*128 + ic*32 + ip)*FP + f0;
      vb0[rep] = *(const uint4*)pB;
      vb1[rep] = *(const uint4*)(pB + FP);
    }
    #pragma unroll
    for (int rep = 0; rep < 4; ++rep){
      int q = tid + rep*THREADS;
      int r0 = q >> 4;
      int ip = (q & 15) << 1;
      unsigned sw = (unsigned)((r0 & 7) << 4);
      const unsigned* a0 = (const unsigned*)&va0[rep];
      const unsigned* a1 = (const unsigned*)&va1[rep];
      const unsigned* b0 = (const unsigned*)&vb0[rep];
      const unsigned* b1 = (const unsigned*)&vb1[rep];
      #pragma unroll
      for (int c = 0; c < 4; ++c){
        unsigned rowb = (unsigned)(c*64 + r0) * 128;     // 128 B per LDS row
        unsigned u0 = a0[c], u1 = a1[c];
        unsigned pr = (u0 & 0xffffu) | (u1 << 16);       // (xr_i, xr_i+1)
        unsigned pi = (u0 >> 16)    | (u1 & 0xffff0000u);// (xi_i, xi_i+1)
        *(unsigned*)(sb + ((rowb + ip*2)      ^ sw)) = pr;      // plane 0 (real)
        *(unsigned*)(sb + ((rowb + 64 + ip*2) ^ sw)) = pi;      // plane 1 (imag)
        u0 = b0[c]; u1 = b1[c];
        pr = (u0 & 0xffffu) | (u1 << 16);
        pi = (u0 >> 16)    | (u1 & 0xffff0000u);
        *(unsigned*)(sb + 32768 + ((rowb + ip*2)      ^ sw)) = pr;
        *(unsigned*)(sb + 32768 + ((rowb + 64 + ip*2) ^ sw)) = pi;
      }
    }
    __syncthreads();
    // ---- compute: per f-bin, 4 MFMA per (mt,nt) tile ----
    #pragma unroll
    for (int c = 0; c < 4; ++c){
      f16x8 xr[2], xi[2], xn[2], bp[2], bq[2];
      #pragma unroll
      for (int mt = 0; mt < 2; ++mt){
        int bb = wm*32 + mt*16 + l15;
        unsigned sw2 = (unsigned)((bb & 7) << 4);
        unsigned rowb = (unsigned)(c*64 + bb) * 128;
        xr[mt] = *(const f16x8*)(sb + ((rowb + l4*16)      ^ sw2));
        xi[mt] = *(const f16x8*)(sb + ((rowb + 64 + l4*16) ^ sw2));
        xn[mt] = -xr[mt];
      }
      #pragma unroll
      for (int nt = 0; nt < 2; ++nt){
        int oo = wn*32 + nt*16 + l15;
        unsigned sw2 = (unsigned)((oo & 7) << 4);
        unsigned rowb = (unsigned)(c*64 + oo) * 128;
        bp[nt] = *(const f16x8*)(sb + 32768 + ((rowb + l4*16)      ^ sw2));
        bq[nt] = *(const f16x8*)(sb + 32768 + ((rowb + 64 + l4*16) ^ sw2));
      }
      #pragma unroll
      for (int mt = 0; mt < 2; ++mt)
        #pragma unroll
        for (int nt = 0; nt < 2; ++nt){
          accR[mt][nt][c] = __builtin_amdgcn_mfma_f32_16x16x32_f16(xr[mt], bp[nt], accR[mt][nt][c], 0, 0, 0);
          accR[mt][nt][c] = __builtin_amdgcn_mfma_f32_16x16x32_f16(xi[mt], bq[nt], accR[mt][nt][c], 0, 0, 0);
          accI[mt][nt][c] = __builtin_amdgcn_mfma_f32_16x16x32_f16(xi[mt], bp[nt], accI[mt][nt][c], 0, 0, 0);
          accI[mt][nt][c] = __builtin_amdgcn_mfma_f32_16x16x32_f16(xn[mt], bq[nt], accI[mt][nt][c], 0, 0, 0);
        }
    }
  }
  // ---- epilogue: accs -> LDS [4][64][65] half2 -> coalesced 16B global stores ----
  __syncthreads();
  __half2* Yl = (__half2*)sb;
  #pragma unroll
  for (int mt = 0; mt < 2; ++mt)
    #pragma unroll
    for (int nt = 0; nt < 2; ++nt){
      int ol = wn*32 + nt*16 + l15;
      #pragma unroll
      for (int c = 0; c < 4; ++c)
        #pragma unroll
        for (int r = 0; r < 4; ++r){
          int bbl = wm*32 + mt*16 + l4*4 + r;
          Yl[(c*64 + bbl)*65 + ol] = pack2(accR[mt][nt][c][r], accI[mt][nt][c][r]);
        }
    }
  __syncthreads();
  #pragma unroll
  for (int rep = 0; rep < 16; ++rep){
    int idx = tid + rep*THREADS;
    int bbl = idx >> 6, ol = idx & 63;
    H2x4 hv;
    #pragma unroll
    for (int c = 0; c < 4; ++c) hv.h[c] = Yl[(c*64 + bbl)*65 + ol];
    *(H2x4*)(Yc + ((size_t)(bb0 + bbl)*OC + (o0 + ol))*FP + f0) = hv;
  }
}

// Y[bb,o,f] = sum_i X[bb,i,f]*conj(W[o,i,f]).  Tile: 8f x 16bb x TO o.
// grid = (BC/16, FP/8, OC/TO). Yc row = bb_local*OC + o_local.
// (VALU fallback for small-workspace chunk modes.)
template<int TO>
__global__ __launch_bounds__(THREADS) void keinsum(const __half2* __restrict__ Xc,
                                                   const __half2* __restrict__ Wc,
                                                   __half2* __restrict__ Yc, int OC){
  constexpr int OGN = TO/4;       // og groups
  constexpr int BB_PER = TO/8;    // bb per thread (bg groups = 128/TO)
  __shared__ float2 Xs[16*64];    // [bb][ii*8+f]
  __shared__ float2 Ws[TO*67];    // [o][ii*8+f], stride 67
  const int bb0 = blockIdx.x * 16;
  const int f0  = blockIdx.y * 8;
  const int o0  = blockIdx.z * TO;
  const int tid = threadIdx.x;
  const int f_id = tid & 7;
  const int g  = tid >> 3;
  const int og = g & (OGN - 1);
  const int bg = g / OGN;
  float2 acc[BB_PER][4];
  #pragma unroll
  for (int a_ = 0; a_ < BB_PER; ++a_)
    #pragma unroll
    for (int b_ = 0; b_ < 4; ++b_) acc[a_][b_] = f2(0.f, 0.f);

  for (int ic = 0; ic < 16; ++ic){
    __syncthreads();
    #pragma unroll
    for (int l = 0; l < TO/16; ++l){      // W chunk: TO*16 float4-sized pieces
      int u = l*THREADS + tid;
      int o = u >> 4, ii = (u >> 1) & 7, c = u & 1;
      H2x4 v = *(const H2x4*)(Wc + (size_t)((o0 + o)*128 + ic*8 + ii)*FP + f0 + c*4);
      #pragma unroll
      for (int j = 0; j < 4; ++j) Ws[o*67 + ii*8 + c*4 + j] = unpack2(v.h[j]);
    }
    {                                     // X chunk: 256 pieces, 1 iter
      int u = tid;
      int bbi = u >> 4, ii = (u >> 1) & 7, c = u & 1;
      H2x4 v = *(const H2x4*)(Xc + (size_t)((bb0 + bbi)*128 + ic*8 + ii)*FP + f0 + c*4);
      #pragma unroll
      for (int j = 0; j < 4; ++j) Xs[bbi*64 + ii*8 + c*4 + j] = unpack2(v.h[j]);
    }
    __syncthreads();
    #pragma unroll
    for (int ii = 0; ii < 8; ++ii){
      float2 xv[BB_PER], wv[4];
      #pragma unroll
      for (int bj = 0; bj < BB_PER; ++bj) xv[bj] = Xs[(bg*BB_PER + bj)*64 + ii*8 + f_id];
      #pragma unroll
      for (int oj = 0; oj < 4; ++oj) wv[oj] = Ws[(og*4 + oj)*67 + ii*8 + f_id];
      #pragma unroll
      for (int bj = 0; bj < BB_PER; ++bj)
        #pragma unroll
        for (int oj = 0; oj < 4; ++oj){
          acc[bj][oj].x += xv[bj].x*wv[oj].x + xv[bj].y*wv[oj].y;  // X*conj(W)
          acc[bj][oj].y += xv[bj].y*wv[oj].x - xv[bj].x*wv[oj].y;
        }
    }
  }
  #pragma unroll
  for (int bj = 0; bj < BB_PER; ++bj)
    #pragma unroll
    for (int oj = 0; oj < 4; ++oj){
      int row = (bb0 + bg*BB_PER + bj)*OC + (o0 + og*4 + oj);
      Yc[(size_t)row*FP + f0 + f_id] = pack2(acc[bj][oj].x, acc[bj][oj].y);
    }
}

// Inverse real FFT + scatter + bias. lr = bb_local*OC + o_local.
__global__ __launch_bounds__(THREADS) void kifft(const __half2* __restrict__ Yc,
                                                 const float* __restrict__ bias,
                                                 float* __restrict__ out,
                                                 int bb_base, int o_base, int oc_shift){
  __shared__ float2 A[2048]; __shared__ float2 B[2048];
  __shared__ float XMs;
  int lr = blockIdx.x;
  int OCm = (1 << oc_shift) - 1;
  int bb = bb_base + (lr >> oc_shift);
  int o  = o_base + (lr & OCm);
  int b = bb >> 2, blk = bb & 3;
  int tid = threadIdx.x;
  const __half2* Y = Yc + (size_t)lr * FP;
  #pragma unroll
  for (int l = 0; l < 2; ++l){
    int u = l*THREADS + tid;            // 4-bin piece
    H2x4 v = *(const H2x4*)(Y + u*4);
    #pragma unroll
    for (int j = 0; j < 4; ++j) B[u*4 + j] = unpack2(v.h[j]);
  }
  if (tid == 0) XMs = __low2float(Y[2048]);
  __syncthreads();
  for (int k = tid; k < 2048; k += THREADS){   // rebuild packed spectrum Z
    float2 xk = B[k];
    float2 xm = (k == 0) ? f2(XMs, 0.f) : B[2048 - k];
    float ar = 0.5f*(xk.x + xm.x);
    float ai = 0.5f*(xk.y - xm.y);
    float dr = 0.5f*(xk.x - xm.x);
    float di = 0.5f*(xk.y + xm.y);
    float rev = (float)k * (1.0f/4096.0f);     // W_4096^{-k}
    float sw = __builtin_amdgcn_sinf(rev);
    float cw = __builtin_amdgcn_cosf(rev);
    float br = dr*cw - di*sw;
    float bi = dr*sw + di*cw;
    A[k] = f2(ar - bi, ai + br);               // Z = A + jB
  }
  float2* z = fft2048(A, B, tid, +1.0f);
  const float s = 1.0f/2048.0f;
  const float bv = bias[o];
  float* op = out + (size_t)(b*128 + o)*8193 + blk*2048;
  for (int n = tid; n < 2048; n += THREADS){
    if (n < 1024){
      op[2*n]     = z[n].x*s + bv;
      op[2*n + 1] = z[n].y*s + bv;
    } else if (n == 1024 && blk == 3){
      op[2048] = z[n].x*s + bv;                // final sample t = 8192
    }
  }
}

extern "C" void kernel_launch(void* const* d_in, const int* in_sizes, int n_in,
                              void* d_out, int out_size, void* d_ws, size_t ws_size,
                              hipStream_t stream){
  (void)in_sizes; (void)n_in; (void)out_size;
  const float* sig  = (const float*)d_in[0];
  const float* wgt  = (const float*)d_in[1];
  const float* bias = (const float*)d_in[2];
  float* out = (float*)d_out;
  const size_t rowb = (size_t)FP * sizeof(__half2);  // 8224 B per spectral row

  // Pick largest (OC, BC) chunking that fits ws_size.
  static const int modes[7][2] = {{128,128},{128,64},{128,32},{128,16},{64,16},{32,16},{16,16}};
  int OC = 0, BC = 0;
  for (int m = 0; m < 7; ++m){
    size_t need = ((size_t)modes[m][0]*128 + (size_t)modes[m][1]*128 +
                   (size_t)modes[m][1]*modes[m][0]) * rowb;
    if (need <= ws_size){ OC = modes[m][0]; BC = modes[m][1]; break; }
  }
  if (!OC) return;  // ws too small even for 35.8 MB plan — fail loudly via poison
  int ocs = 0; while ((1 << ocs) != OC) ++ocs;

  char* ws = (char*)d_ws;
  __half2* Wc = (__half2*)ws;
  __half2* Xc = (__half2*)(ws + (size_t)OC*128*rowb);
  __half2* Yc = (__half2*)(ws + ((size_t)OC*128 + (size_t)BC*128)*rowb);

  for (int ob = 0; ob < 128; ob += OC){
    hipLaunchKernelGGL(kfft_w, dim3(OC*128), dim3(THREADS), 0, stream, wgt, Wc, ob);
    for (int bbb = 0; bbb < 128; bbb += BC){
      hipLaunchKernelGGL(kfft_s, dim3(BC*128), dim3(THREADS), 0, stream, sig, Xc, bbb);
      if ((BC & 63) == 0 && (OC & 63) == 0){
        int nbb = BC >> 6, no = OC >> 6;
        hipLaunchKernelGGL(kceinsum, dim3(nbb*no*(FP/4)), dim3(THREADS), 0, stream,
                           Xc, Wc, Yc, nbb, OC);
      } else {
        dim3 ge(BC/16, FP/8, OC >= 64 ? OC/64 : 1);
        if (OC >= 64)
          hipLaunchKernelGGL(HIP_KERNEL_NAME(keinsum<64>), ge, dim3(THREADS), 0, stream, Xc, Wc, Yc, OC);
        else if (OC == 32)
          hipLaunchKernelGGL(HIP_KERNEL_NAME(keinsum<32>), ge, dim3(THREADS), 0, stream, Xc, Wc, Yc, OC);
        else
          hipLaunchKernelGGL(HIP_KERNEL_NAME(keinsum<16>), ge, dim3(THREADS), 0, stream, Xc, Wc, Yc, OC);
      }
      hipLaunchKernelGGL(kifft, dim3(BC*OC), dim3(THREADS), 0, stream, Yc, bias, out, bbb, ob, ocs);
    }
  }
}

// Round 2
// 939.940 us; speedup vs baseline: 1.7986x; 1.1320x over previous
//
#include <hip/hip_runtime.h>
#include <hip/hip_fp16.h>

// FFT cross-correlation via overlap-save, fp16 spectra, ws-size-adaptive chunking.
// signal (32,128,8192) f32, weight (128,128,2048) f32, bias (128) f32
// out[b,o,t] = sum_i sum_k s_pad[b,i,t+k]*w[o,i,k] + bias[o], t in [0,8192]
// Blocks of 4096 (hop 2048, 4 per batch row); real FFT via packed complex
// Stockham FFT of M=2048 (natural order). Spectra stored as __half2 (4B/bin).
// Round 2: interleaved-K complex MFMA einsum (32KB LDS, 16 waves/CU),
//          Yc layout [bb][fb][o][c] for full-line stores, XCD f-slab ordering,
//          register-prefetch pipeline.

#define THREADS 256
#define CTHREADS 512
#define FP 2056   // padded bins per row (valid f=0..2048); row = 8224 B, 16B-aligned
#define NFB 514   // FP/4 f-blocks

struct alignas(16) H2x4 { __half2 h[4]; };

typedef _Float16 f16x8 __attribute__((ext_vector_type(8)));
typedef float f32x4 __attribute__((ext_vector_type(4)));

__device__ __forceinline__ float2 f2(float x, float y){ return make_float2(x, y); }
__device__ __forceinline__ __half2 pack2(float x, float y){ return __floats2half2_rn(x, y); }
__device__ __forceinline__ float2 unpack2(__half2 h){
  return make_float2(__low2float(h), __high2float(h));
}

// In-LDS Stockham radix-2 complex FFT, size 2048, 256 threads.
// sign=-1 fwd, +1 inv (unscaled). Twiddles via v_sin/v_cos (revolutions).
__device__ float2* fft2048(float2* A, float2* B, int tid, float sign){
  float2* src = A; float2* dst = B;
  #pragma unroll 1
  for (int s = 0; s < 11; ++s){
    const int Ls = 1 << s;
    const float crev = sign * 0.5f / (float)Ls;  // rev per p: angle = sign*pi*p/Ls
    __syncthreads();
    #pragma unroll
    for (int r = 0; r < 4; ++r){
      int j = tid + (r << 8);
      int p = j & (Ls - 1);
      int q = j >> s;
      float rev = crev * (float)p;
      float sw = __builtin_amdgcn_sinf(rev);
      float cw = __builtin_amdgcn_cosf(rev);
      float2 a = src[j];
      float2 b = src[j + 1024];
      float tr = b.x*cw - b.y*sw;
      float ti = b.x*sw + b.y*cw;
      int o0 = (q << (s+1)) + p;
      dst[o0]      = f2(a.x + tr, a.y + ti);
      dst[o0 + Ls] = f2(a.x - tr, a.y - ti);
    }
    float2* t = src; src = dst; dst = t;
  }
  __syncthreads();
  return src;
}

// Packed spectrum Z (M=2048) -> rfft bins X[0..2048] of length-4096 real seq,
// stored fp16 to global row; zero the pad bins 2049..2055.
__device__ void unpack_store(const float2* Z, __half2* out, int tid){
  for (int k = tid; k < 2048; k += THREADS){
    float2 zk = Z[k];
    float2 zm = Z[(2048 - k) & 2047];
    float ar =  0.5f*(zk.x + zm.x);
    float ai =  0.5f*(zk.y - zm.y);
    float br =  0.5f*(zk.y + zm.y);
    float bi = -0.5f*(zk.x - zm.x);
    float rev = -(float)k * (1.0f/4096.0f);   // W_4096^k
    float sw = __builtin_amdgcn_sinf(rev);
    float cw = __builtin_amdgcn_cosf(rev);
    out[k] = pack2(ar + cw*br - sw*bi, ai + cw*bi + sw*br);
  }
  if (tid == 0){
    float2 z0 = Z[0];
    out[2048] = pack2(z0.x - z0.y, 0.0f);     // Nyquist
  }
  if (tid >= 1 && tid < 8) out[2048 + tid] = pack2(0.0f, 0.0f);
}

// Weight FFT for o-chunk: local row = o_local*128+i, global o = o_base+o_local.
__global__ __launch_bounds__(THREADS) void kfft_w(const float* __restrict__ w,
                                                  __half2* __restrict__ Wc, int o_base){
  __shared__ float2 A[2048]; __shared__ float2 B[2048];
  int lr = blockIdx.x;
  int grow = (o_base + (lr >> 7)) * 128 + (lr & 127);
  const float2* wv = (const float2*)(w + (size_t)grow * 2048);
  for (int n = threadIdx.x; n < 2048; n += THREADS)
    A[n] = (n < 1024) ? wv[n] : f2(0.f, 0.f);
  float2* Z = fft2048(A, B, threadIdx.x, -1.0f);
  unpack_store(Z, Wc + (size_t)lr * FP, threadIdx.x);
}

// Signal block FFT for bb-chunk: local row = bb_local*128+i, bb = bb_base+bb_local,
// bb = b*4+blk. x[m]=s_pad[blk*2048+m]; float2 idx q = n + blk*1024 - 512.
__global__ __launch_bounds__(THREADS) void kfft_s(const float* __restrict__ sig,
                                                  __half2* __restrict__ Xc, int bb_base){
  __shared__ float2 A[2048]; __shared__ float2 B[2048];
  int lr = blockIdx.x;
  int bb = bb_base + (lr >> 7), i = lr & 127;
  int b = bb >> 2, blk = bb & 3;
  const float2* sv = (const float2*)(sig + (size_t)(b*128 + i) * 8192);
  for (int n = threadIdx.x; n < 2048; n += THREADS){
    int q = n + blk*1024 - 512;
    A[n] = (q >= 0 && q < 4096) ? sv[q] : f2(0.f, 0.f);
  }
  float2* Z = fft2048(A, B, threadIdx.x, -1.0f);
  unpack_store(Z, Xc + (size_t)lr * FP, threadIdx.x);
}

// ---------------------------------------------------------------------------
// MFMA complex einsum: Y[bb,o,f] = sum_i X[bb,i,f]*conj(W[o,i,f]).
// Interleaved-K scheme: MFMA K=32 halfs = 16 i as (re,im) pairs (the native
// __half2 storage order — no de-interleave repack).
//   acc_r = sum xr*wr + xi*wi           (A, B as stored)
//   acc_i = sum xi*wr - xr*wi = A . B2, B2 word = rot16(B) ^ 0x00008000
// Block: 512 thr (8 waves, 2x4), tile 64bb x 64o x 4f, wave subtile 32x16.
// K chunk = 16 i, 8 chunks, LDS 32 KB single-buffer, reg-prefetch pipeline.
// LDS rows 128 B (two f-bins), XOR-swizzle ((row&7)<<4).
// Yc layout: ((bb*514 + fb)*OC + o)*4 + c  -> 256 B contiguous store chunks.
// Grid order: x-inner/y-outer + chunked XCD slab => each XCD owns a disjoint
// f-slab of ALL spatial tiles (compulsory-only HBM fetch).
// ---------------------------------------------------------------------------
__global__ __launch_bounds__(CTHREADS, 4) void kceinsum(
    const __half2* __restrict__ Xc, const __half2* __restrict__ Wc,
    __half2* __restrict__ Yc, int nbbBlk, int OC)
{
  __shared__ char sb[32768] __attribute__((aligned(16)));
  const int total = gridDim.x;
  const int nt = total / NFB;                  // spatial tiles
  int wg = blockIdx.x;
  int w = ((total & 7) == 0) ? ((wg & 7) * (total >> 3) + (wg >> 3)) : wg;
  const int x = w % nt;                        // tile: consecutive w covers all tiles
  const int y = w / nt;                        // f-block (slab-major per XCD)
  const int bb0 = (x % nbbBlk) * 64;
  const int o0  = (x / nbbBlk) * 64;
  const int f0  = y * 4;

  const int tid = threadIdx.x;
  const int wave = tid >> 6, lane = tid & 63;
  const int wm = wave >> 2;                    // bb half (0..1)
  const int wn = wave & 3;                     // o quarter (0..3)
  const int l15 = lane & 15, l4 = lane >> 4;

  // staging assignment: each thread owns one (row, i-pair) unit of A and of B
  const int r0  = (tid >> 3) & 63;             // staged row 0..63
  const int ip2 = tid & 7;                     // i-pair 0..7 (i = 2*ip2)
  const __half2* pA = Xc + ((size_t)(bb0 + r0) * 128 + ip2 * 2) * FP + f0;
  const __half2* pB = Wc + ((size_t)(o0 + r0) * 128 + ip2 * 2) * FP + f0;

  const f32x4 zv = {0.f, 0.f, 0.f, 0.f};
  f32x4 accR[2][4], accI[2][4];
  #pragma unroll
  for (int mt = 0; mt < 2; ++mt)
    #pragma unroll
    for (int c = 0; c < 4; ++c){ accR[mt][c] = zv; accI[mt][c] = zv; }

  // prologue: load chunk 0
  uint4 va0 = *(const uint4*)pA;
  uint4 va1 = *(const uint4*)(pA + FP);
  uint4 vb0 = *(const uint4*)pB;
  uint4 vb1 = *(const uint4*)(pB + FP);

  const unsigned wswz = ((unsigned)(r0 & 7)) << 4;

  #pragma unroll 1
  for (int ic = 0; ic < 8; ++ic){
    __syncthreads();                            // LDS free (compute ic-1 done)
    {   // write staged regs -> LDS (planes by f-bin c; pair c's into 128 B rows)
      const unsigned* a0 = (const unsigned*)&va0;
      const unsigned* a1 = (const unsigned*)&va1;
      const unsigned* b0 = (const unsigned*)&vb0;
      const unsigned* b1 = (const unsigned*)&vb1;
      #pragma unroll
      for (int c = 0; c < 4; ++c){
        unsigned off = ((((unsigned)r0 << 7) + ((unsigned)(c & 1) << 6) +
                         ((unsigned)ip2 << 3)) ^ wswz) + (((unsigned)(c >> 1)) << 13);
        *(uint2*)(sb + off)         = make_uint2(a0[c], a1[c]);
        *(uint2*)(sb + 16384 + off) = make_uint2(b0[c], b1[c]);
      }
    }
    if (ic < 7){                                // prefetch chunk ic+1 (in flight
      const __half2* qA = pA + (size_t)(ic + 1) * 16 * FP;      // across compute)
      const __half2* qB = pB + (size_t)(ic + 1) * 16 * FP;
      va0 = *(const uint4*)qA;
      va1 = *(const uint4*)(qA + FP);
      vb0 = *(const uint4*)qB;
      vb1 = *(const uint4*)(qB + FP);
    }
    __syncthreads();
    // compute: per f-bin c: 2 A-frags (mt), 1 B-frag + rot16^sign variant
    #pragma unroll
    for (int c = 0; c < 4; ++c){
      const unsigned cb = (((unsigned)(c >> 1)) << 13);
      const unsigned cf = ((unsigned)(c & 1)) << 6;
      f16x8 af[2];
      #pragma unroll
      for (int mt = 0; mt < 2; ++mt){
        unsigned row = (unsigned)(wm*32 + mt*16 + l15);
        unsigned off = ((row << 7) + cf + ((unsigned)l4 << 4)) ^ ((row & 7) << 4);
        af[mt] = *(const f16x8*)(sb + cb + off);
      }
      unsigned orow = (unsigned)(wn*16 + l15);
      unsigned offb = ((orow << 7) + cf + ((unsigned)l4 << 4)) ^ ((orow & 7) << 4);
      f16x8 bf = *(const f16x8*)(sb + 16384 + cb + offb);
      union { f16x8 v; unsigned u[4]; } sB, dB;
      sB.v = bf;
      #pragma unroll
      for (int j = 0; j < 4; ++j)
        dB.u[j] = ((sB.u[j] >> 16) | (sB.u[j] << 16)) ^ 0x00008000u;  // (-wi, wr)
      #pragma unroll
      for (int mt = 0; mt < 2; ++mt){
        accR[mt][c] = __builtin_amdgcn_mfma_f32_16x16x32_f16(af[mt], bf,   accR[mt][c], 0, 0, 0);
        accI[mt][c] = __builtin_amdgcn_mfma_f32_16x16x32_f16(af[mt], dB.v, accI[mt][c], 0, 0, 0);
      }
    }
  }
  // epilogue: direct 16 B stores; lanes l15 -> 16 consecutive o = 256 B chunks
  const int olg = o0 + wn*16 + l15;
  #pragma unroll
  for (int mt = 0; mt < 2; ++mt)
    #pragma unroll
    for (int r = 0; r < 4; ++r){
      int bbl = bb0 + wm*32 + mt*16 + l4*4 + r;
      H2x4 hv;
      #pragma unroll
      for (int c = 0; c < 4; ++c) hv.h[c] = pack2(accR[mt][c][r], accI[mt][c][r]);
      *(H2x4*)(Yc + ((size_t)bbl * NFB + y) * OC * 4 + (size_t)olg * 4) = hv;
    }
}

// Y[bb,o,f] = sum_i X[bb,i,f]*conj(W[o,i,f]).  Tile: 8f x 16bb x TO o.
// grid = (BC/16, FP/8, OC/TO). Yc row = bb_local*OC + o_local (OLD layout).
// (VALU fallback for small-workspace chunk modes.)
template<int TO>
__global__ __launch_bounds__(THREADS) void keinsum(const __half2* __restrict__ Xc,
                                                   const __half2* __restrict__ Wc,
                                                   __half2* __restrict__ Yc, int OC){
  constexpr int OGN = TO/4;       // og groups
  constexpr int BB_PER = TO/8;    // bb per thread (bg groups = 128/TO)
  __shared__ float2 Xs[16*64];    // [bb][ii*8+f]
  __shared__ float2 Ws[TO*67];    // [o][ii*8+f], stride 67
  const int bb0 = blockIdx.x * 16;
  const int f0  = blockIdx.y * 8;
  const int o0  = blockIdx.z * TO;
  const int tid = threadIdx.x;
  const int f_id = tid & 7;
  const int g  = tid >> 3;
  const int og = g & (OGN - 1);
  const int bg = g / OGN;
  float2 acc[BB_PER][4];
  #pragma unroll
  for (int a_ = 0; a_ < BB_PER; ++a_)
    #pragma unroll
    for (int b_ = 0; b_ < 4; ++b_) acc[a_][b_] = f2(0.f, 0.f);

  for (int ic = 0; ic < 16; ++ic){
    __syncthreads();
    #pragma unroll
    for (int l = 0; l < TO/16; ++l){      // W chunk: TO*16 float4-sized pieces
      int u = l*THREADS + tid;
      int o = u >> 4, ii = (u >> 1) & 7, c = u & 1;
      H2x4 v = *(const H2x4*)(Wc + (size_t)((o0 + o)*128 + ic*8 + ii)*FP + f0 + c*4);
      #pragma unroll
      for (int j = 0; j < 4; ++j) Ws[o*67 + ii*8 + c*4 + j] = unpack2(v.h[j]);
    }
    {                                     // X chunk: 256 pieces, 1 iter
      int u = tid;
      int bbi = u >> 4, ii = (u >> 1) & 7, c = u & 1;
      H2x4 v = *(const H2x4*)(Xc + (size_t)((bb0 + bbi)*128 + ic*8 + ii)*FP + f0 + c*4);
      #pragma unroll
      for (int j = 0; j < 4; ++j) Xs[bbi*64 + ii*8 + c*4 + j] = unpack2(v.h[j]);
    }
    __syncthreads();
    #pragma unroll
    for (int ii = 0; ii < 8; ++ii){
      float2 xv[BB_PER], wv[4];
      #pragma unroll
      for (int bj = 0; bj < BB_PER; ++bj) xv[bj] = Xs[(bg*BB_PER + bj)*64 + ii*8 + f_id];
      #pragma unroll
      for (int oj = 0; oj < 4; ++oj) wv[oj] = Ws[(og*4 + oj)*67 + ii*8 + f_id];
      #pragma unroll
      for (int bj = 0; bj < BB_PER; ++bj)
        #pragma unroll
        for (int oj = 0; oj < 4; ++oj){
          acc[bj][oj].x += xv[bj].x*wv[oj].x + xv[bj].y*wv[oj].y;  // X*conj(W)
          acc[bj][oj].y += xv[bj].y*wv[oj].x - xv[bj].x*wv[oj].y;
        }
    }
  }
  #pragma unroll
  for (int bj = 0; bj < BB_PER; ++bj)
    #pragma unroll
    for (int oj = 0; oj < 4; ++oj){
      int row = (bb0 + bg*BB_PER + bj)*OC + (o0 + og*4 + oj);
      Yc[(size_t)row*FP + f0 + f_id] = pack2(acc[bj][oj].x, acc[bj][oj].y);
    }
}

// Inverse real FFT + scatter + bias. lr = bb_local*OC + o_local.
// newlay=1: Yc layout ((bbl*514 + fb)*OC + ol)*4 + c  (kceinsum path)
// newlay=0: Yc row-major lr*FP (fallback keinsum path)
__global__ __launch_bounds__(THREADS) void kifft(const __half2* __restrict__ Yc,
                                                 const float* __restrict__ bias,
                                                 float* __restrict__ out,
                                                 int bb_base, int o_base, int oc_shift,
                                                 int newlay){
  __shared__ float2 A[2048]; __shared__ float2 B[2048];
  __shared__ float XMs;
  int lr = blockIdx.x;
  int OCm = (1 << oc_shift) - 1;
  int bbl = lr >> oc_shift, ol = lr & OCm;
  int bb = bb_base + bbl;
  int o  = o_base + ol;
  int b = bb >> 2, blk = bb & 3;
  int tid = threadIdx.x;
  if (newlay){
    const size_t ustr = (size_t)(OCm + 1) * 4;            // half2 stride per f-block
    const __half2* Yb = Yc + (size_t)bbl * NFB * ustr + (size_t)ol * 4;
    #pragma unroll
    for (int l = 0; l < 2; ++l){
      int u = l*THREADS + tid;            // f-block u -> bins 4u..4u+3
      H2x4 v = *(const H2x4*)(Yb + (size_t)u * ustr);
      #pragma unroll
      for (int j = 0; j < 4; ++j) B[u*4 + j] = unpack2(v.h[j]);
    }
    if (tid == 0) XMs = __low2float(Yb[512 * ustr]);      // bin 2048
  } else {
    const __half2* Y = Yc + (size_t)lr * FP;
    #pragma unroll
    for (int l = 0; l < 2; ++l){
      int u = l*THREADS + tid;            // 4-bin piece
      H2x4 v = *(const H2x4*)(Y + u*4);
      #pragma unroll
      for (int j = 0; j < 4; ++j) B[u*4 + j] = unpack2(v.h[j]);
    }
    if (tid == 0) XMs = __low2float(Y[2048]);
  }
  __syncthreads();
  for (int k = tid; k < 2048; k += THREADS){   // rebuild packed spectrum Z
    float2 xk = B[k];
    float2 xm = (k == 0) ? f2(XMs, 0.f) : B[2048 - k];
    float ar = 0.5f*(xk.x + xm.x);
    float ai = 0.5f*(xk.y - xm.y);
    float dr = 0.5f*(xk.x - xm.x);
    float di = 0.5f*(xk.y + xm.y);
    float rev = (float)k * (1.0f/4096.0f);     // W_4096^{-k}
    float sw = __builtin_amdgcn_sinf(rev);
    float cw = __builtin_amdgcn_cosf(rev);
    float br = dr*cw - di*sw;
    float bi = dr*sw + di*cw;
    A[k] = f2(ar - bi, ai + br);               // Z = A + jB
  }
  float2* z = fft2048(A, B, tid, +1.0f);
  const float s = 1.0f/2048.0f;
  const float bv = bias[o];
  float* op = out + (size_t)(b*128 + o)*8193 + blk*2048;
  for (int n = tid; n < 2048; n += THREADS){
    if (n < 1024){
      op[2*n]     = z[n].x*s + bv;
      op[2*n + 1] = z[n].y*s + bv;
    } else if (n == 1024 && blk == 3){
      op[2048] = z[n].x*s + bv;                // final sample t = 8192
    }
  }
}

extern "C" void kernel_launch(void* const* d_in, const int* in_sizes, int n_in,
                              void* d_out, int out_size, void* d_ws, size_t ws_size,
                              hipStream_t stream){
  (void)in_sizes; (void)n_in; (void)out_size;
  const float* sig  = (const float*)d_in[0];
  const float* wgt  = (const float*)d_in[1];
  const float* bias = (const float*)d_in[2];
  float* out = (float*)d_out;
  const size_t rowb = (size_t)FP * sizeof(__half2);  // 8224 B per spectral row

  // Pick largest (OC, BC) chunking that fits ws_size.
  static const int modes[7][2] = {{128,128},{128,64},{128,32},{128,16},{64,16},{32,16},{16,16}};
  int OC = 0, BC = 0;
  for (int m = 0; m < 7; ++m){
    size_t need = ((size_t)modes[m][0]*128 + (size_t)modes[m][1]*128 +
                   (size_t)modes[m][1]*modes[m][0]) * rowb;
    if (need <= ws_size){ OC = modes[m][0]; BC = modes[m][1]; break; }
  }
  if (!OC) return;  // ws too small even for 35.8 MB plan — fail loudly via poison
  int ocs = 0; while ((1 << ocs) != OC) ++ocs;

  char* ws = (char*)d_ws;
  __half2* Wc = (__half2*)ws;
  __half2* Xc = (__half2*)(ws + (size_t)OC*128*rowb);
  __half2* Yc = (__half2*)(ws + ((size_t)OC*128 + (size_t)BC*128)*rowb);

  for (int ob = 0; ob < 128; ob += OC){
    hipLaunchKernelGGL(kfft_w, dim3(OC*128), dim3(THREADS), 0, stream, wgt, Wc, ob);
    for (int bbb = 0; bbb < 128; bbb += BC){
      hipLaunchKernelGGL(kfft_s, dim3(BC*128), dim3(THREADS), 0, stream, sig, Xc, bbb);
      int newlay = ((BC & 63) == 0 && (OC & 63) == 0) ? 1 : 0;
      if (newlay){
        int nbb = BC >> 6, no = OC >> 6;
        hipLaunchKernelGGL(kceinsum, dim3(nbb*no*NFB), dim3(CTHREADS), 0, stream,
                           Xc, Wc, Yc, nbb, OC);
      } else {
        dim3 ge(BC/16, FP/8, OC >= 64 ? OC/64 : 1);
        if (OC >= 64)
          hipLaunchKernelGGL(HIP_KERNEL_NAME(keinsum<64>), ge, dim3(THREADS), 0, stream, Xc, Wc, Yc, OC);
        else if (OC == 32)
          hipLaunchKernelGGL(HIP_KERNEL_NAME(keinsum<32>), ge, dim3(THREADS), 0, stream, Xc, Wc, Yc, OC);
        else
          hipLaunchKernelGGL(HIP_KERNEL_NAME(keinsum<16>), ge, dim3(THREADS), 0, stream, Xc, Wc, Yc, OC);
      }
      hipLaunchKernelGGL(kifft, dim3(BC*OC), dim3(THREADS), 0, stream, Yc, bias, out, bbb, ob, ocs, newlay);
    }
  }
}

// Round 3
// 856.595 us; speedup vs baseline: 1.9736x; 1.0973x over previous
//
#include <hip/hip_runtime.h>
#include <hip/hip_fp16.h>

// FFT cross-correlation via overlap-save, fp16 spectra, ws-size-adaptive chunking.
// signal (32,128,8192) f32, weight (128,128,2048) f32, bias (128) f32
// out[b,o,t] = sum_i sum_k s_pad[b,i,t+k]*w[o,i,k] + bias[o], t in [0,8192]
// Blocks of 4096 (hop 2048, 4 per batch row); real FFT via packed complex
// Stockham FFT of M=2048 (natural order). Spectra stored as __half2 (4B/bin).
// Round 2: interleaved-K complex MFMA einsum (32KB LDS, 16 waves/CU),
//          Yc layout [bb][fb][o][c] for full-line stores, XCD f-slab ordering.
// Round 3: radix-4 Stockham FFT (5x r4 + 1x r2): sincos/thread 44->14,
//          LDS stage traffic 352->192 KB, barriers 12->7.

#define THREADS 256
#define CTHREADS 512
#define FP 2056   // padded bins per row (valid f=0..2048); row = 8224 B, 16B-aligned
#define NFB 514   // FP/4 f-blocks

struct alignas(16) H2x4 { __half2 h[4]; };

typedef _Float16 f16x8 __attribute__((ext_vector_type(8)));
typedef float f32x4 __attribute__((ext_vector_type(4)));

__device__ __forceinline__ float2 f2(float x, float y){ return make_float2(x, y); }
__device__ __forceinline__ __half2 pack2(float x, float y){ return __floats2half2_rn(x, y); }
__device__ __forceinline__ float2 unpack2(__half2 h){
  return make_float2(__low2float(h), __high2float(h));
}
__device__ __forceinline__ float2 cmul(float2 a, float2 b){
  return make_float2(a.x*b.x - a.y*b.y, a.x*b.y + a.y*b.x);
}

// In-LDS Stockham complex FFT, size 2048, 256 threads: 5 radix-4 stages + 1
// radix-2 stage. sign=-1 fwd, +1 inv (unscaled). Twiddles via v_sin/v_cos
// (revolutions). Radix-4 stage = composition of two radix-2 Stockham stages
// (L then 2L): wa = e(sign*pi*p/(2L)), w = wa^2, second-half twiddle i*sign*wa.
__device__ float2* fft2048(float2* A, float2* B, int tid, float sign){
  float2* src = A; float2* dst = B;
  #pragma unroll 1
  for (int st = 0; st < 5; ++st){
    const int twos = 2*st;
    const int L = 1 << twos;
    const float crev = sign * 0.25f / (float)L;   // wa rev per p: angle sign*pi*p/(2L)
    __syncthreads();
    #pragma unroll
    for (int r = 0; r < 2; ++r){
      int j = tid + (r << 8);            // 0..511
      int p = j & (L - 1);
      int q = j >> twos;
      float rev = crev * (float)p;
      float sa = __builtin_amdgcn_sinf(rev);
      float ca = __builtin_amdgcn_cosf(rev);
      float2 wa = f2(ca, sa);
      float2 w  = f2(ca*ca - sa*sa, 2.0f*ca*sa);  // wa^2 = radix-2 stage-L twiddle
      float2 x0 = src[j];
      float2 x1 = src[j + 512];
      float2 x2 = src[j + 1024];
      float2 x3 = src[j + 1536];
      float2 t2 = cmul(w, x2);
      float2 t3 = cmul(w, x3);
      float2 u0 = f2(x0.x + t2.x, x0.y + t2.y);
      float2 u1 = f2(x0.x - t2.x, x0.y - t2.y);
      float2 u2 = f2(x1.x + t3.x, x1.y + t3.y);
      float2 u3 = f2(x1.x - t3.x, x1.y - t3.y);
      float2 v2 = cmul(wa, u2);
      float2 v3 = cmul(wa, u3);
      float2 iv3 = f2(-sign * v3.y, sign * v3.x); // i*sign*v3
      int ob = (q << (twos + 2)) + p;
      dst[ob]       = f2(u0.x + v2.x,  u0.y + v2.y);
      dst[ob + L]   = f2(u1.x + iv3.x, u1.y + iv3.y);
      dst[ob + 2*L] = f2(u0.x - v2.x,  u0.y - v2.y);
      dst[ob + 3*L] = f2(u1.x - iv3.x, u1.y - iv3.y);
    }
    float2* t = src; src = dst; dst = t;
  }
  {   // final radix-2 stage, L=1024
    const float crev = sign * 0.5f / 1024.0f;
    __syncthreads();
    #pragma unroll
    for (int r = 0; r < 4; ++r){
      int j = tid + (r << 8);
      float rev = crev * (float)j;
      float sw = __builtin_amdgcn_sinf(rev);
      float cw = __builtin_amdgcn_cosf(rev);
      float2 a = src[j];
      float2 b = src[j + 1024];
      float tr = b.x*cw - b.y*sw;
      float ti = b.x*sw + b.y*cw;
      dst[j]        = f2(a.x + tr, a.y + ti);
      dst[j + 1024] = f2(a.x - tr, a.y - ti);
    }
    float2* t = src; src = dst; dst = t;
  }
  __syncthreads();
  return src;
}

// Packed spectrum Z (M=2048) -> rfft bins X[0..2048] of length-4096 real seq,
// stored fp16 to global row; zero the pad bins 2049..2055.
__device__ void unpack_store(const float2* Z, __half2* out, int tid){
  for (int k = tid; k < 2048; k += THREADS){
    float2 zk = Z[k];
    float2 zm = Z[(2048 - k) & 2047];
    float ar =  0.5f*(zk.x + zm.x);
    float ai =  0.5f*(zk.y - zm.y);
    float br =  0.5f*(zk.y + zm.y);
    float bi = -0.5f*(zk.x - zm.x);
    float rev = -(float)k * (1.0f/4096.0f);   // W_4096^k
    float sw = __builtin_amdgcn_sinf(rev);
    float cw = __builtin_amdgcn_cosf(rev);
    out[k] = pack2(ar + cw*br - sw*bi, ai + cw*bi + sw*br);
  }
  if (tid == 0){
    float2 z0 = Z[0];
    out[2048] = pack2(z0.x - z0.y, 0.0f);     // Nyquist
  }
  if (tid >= 1 && tid < 8) out[2048 + tid] = pack2(0.0f, 0.0f);
}

// Weight FFT for o-chunk: local row = o_local*128+i, global o = o_base+o_local.
__global__ __launch_bounds__(THREADS) void kfft_w(const float* __restrict__ w,
                                                  __half2* __restrict__ Wc, int o_base){
  __shared__ float2 A[2048]; __shared__ float2 B[2048];
  int lr = blockIdx.x;
  int grow = (o_base + (lr >> 7)) * 128 + (lr & 127);
  const float2* wv = (const float2*)(w + (size_t)grow * 2048);
  for (int n = threadIdx.x; n < 2048; n += THREADS)
    A[n] = (n < 1024) ? wv[n] : f2(0.f, 0.f);
  float2* Z = fft2048(A, B, threadIdx.x, -1.0f);
  unpack_store(Z, Wc + (size_t)lr * FP, threadIdx.x);
}

// Signal block FFT for bb-chunk: local row = bb_local*128+i, bb = bb_base+bb_local,
// bb = b*4+blk. x[m]=s_pad[blk*2048+m]; float2 idx q = n + blk*1024 - 512.
__global__ __launch_bounds__(THREADS) void kfft_s(const float* __restrict__ sig,
                                                  __half2* __restrict__ Xc, int bb_base){
  __shared__ float2 A[2048]; __shared__ float2 B[2048];
  int lr = blockIdx.x;
  int bb = bb_base + (lr >> 7), i = lr & 127;
  int b = bb >> 2, blk = bb & 3;
  const float2* sv = (const float2*)(sig + (size_t)(b*128 + i) * 8192);
  for (int n = threadIdx.x; n < 2048; n += THREADS){
    int q = n + blk*1024 - 512;
    A[n] = (q >= 0 && q < 4096) ? sv[q] : f2(0.f, 0.f);
  }
  float2* Z = fft2048(A, B, threadIdx.x, -1.0f);
  unpack_store(Z, Xc + (size_t)lr * FP, threadIdx.x);
}

// ---------------------------------------------------------------------------
// MFMA complex einsum: Y[bb,o,f] = sum_i X[bb,i,f]*conj(W[o,i,f]).
// Interleaved-K scheme: MFMA K=32 halfs = 16 i as (re,im) pairs (the native
// __half2 storage order — no de-interleave repack).
//   acc_r = sum xr*wr + xi*wi           (A, B as stored)
//   acc_i = sum xi*wr - xr*wi = A . B2, B2 word = rot16(B) ^ 0x00008000
// Block: 512 thr (8 waves, 2x4), tile 64bb x 64o x 4f, wave subtile 32x16.
// K chunk = 16 i, 8 chunks, LDS 32 KB single-buffer, reg-prefetch pipeline.
// LDS rows 128 B (two f-bins), XOR-swizzle ((row&7)<<4).
// Yc layout: ((bb*514 + fb)*OC + o)*4 + c  -> 256 B contiguous store chunks.
// Grid order: x-inner/y-outer + chunked XCD slab => each XCD owns a disjoint
// f-slab of ALL spatial tiles (compulsory-only HBM fetch).
// ---------------------------------------------------------------------------
__global__ __launch_bounds__(CTHREADS, 4) void kceinsum(
    const __half2* __restrict__ Xc, const __half2* __restrict__ Wc,
    __half2* __restrict__ Yc, int nbbBlk, int OC)
{
  __shared__ char sb[32768] __attribute__((aligned(16)));
  const int total = gridDim.x;
  const int nt = total / NFB;                  // spatial tiles
  int wg = blockIdx.x;
  int w = ((total & 7) == 0) ? ((wg & 7) * (total >> 3) + (wg >> 3)) : wg;
  const int x = w % nt;                        // tile: consecutive w covers all tiles
  const int y = w / nt;                        // f-block (slab-major per XCD)
  const int bb0 = (x % nbbBlk) * 64;
  const int o0  = (x / nbbBlk) * 64;
  const int f0  = y * 4;

  const int tid = threadIdx.x;
  const int wave = tid >> 6, lane = tid & 63;
  const int wm = wave >> 2;                    // bb half (0..1)
  const int wn = wave & 3;                     // o quarter (0..3)
  const int l15 = lane & 15, l4 = lane >> 4;

  // staging assignment: each thread owns one (row, i-pair) unit of A and of B
  const int r0  = (tid >> 3) & 63;             // staged row 0..63
  const int ip2 = tid & 7;                     // i-pair 0..7 (i = 2*ip2)
  const __half2* pA = Xc + ((size_t)(bb0 + r0) * 128 + ip2 * 2) * FP + f0;
  const __half2* pB = Wc + ((size_t)(o0 + r0) * 128 + ip2 * 2) * FP + f0;

  const f32x4 zv = {0.f, 0.f, 0.f, 0.f};
  f32x4 accR[2][4], accI[2][4];
  #pragma unroll
  for (int mt = 0; mt < 2; ++mt)
    #pragma unroll
    for (int c = 0; c < 4; ++c){ accR[mt][c] = zv; accI[mt][c] = zv; }

  // prologue: load chunk 0
  uint4 va0 = *(const uint4*)pA;
  uint4 va1 = *(const uint4*)(pA + FP);
  uint4 vb0 = *(const uint4*)pB;
  uint4 vb1 = *(const uint4*)(pB + FP);

  const unsigned wswz = ((unsigned)(r0 & 7)) << 4;

  #pragma unroll 1
  for (int ic = 0; ic < 8; ++ic){
    __syncthreads();                            // LDS free (compute ic-1 done)
    {   // write staged regs -> LDS (planes by f-bin c; pair c's into 128 B rows)
      const unsigned* a0 = (const unsigned*)&va0;
      const unsigned* a1 = (const unsigned*)&va1;
      const unsigned* b0 = (const unsigned*)&vb0;
      const unsigned* b1 = (const unsigned*)&vb1;
      #pragma unroll
      for (int c = 0; c < 4; ++c){
        unsigned off = ((((unsigned)r0 << 7) + ((unsigned)(c & 1) << 6) +
                         ((unsigned)ip2 << 3)) ^ wswz) + (((unsigned)(c >> 1)) << 13);
        *(uint2*)(sb + off)         = make_uint2(a0[c], a1[c]);
        *(uint2*)(sb + 16384 + off) = make_uint2(b0[c], b1[c]);
      }
    }
    if (ic < 7){                                // prefetch chunk ic+1 (in flight
      const __half2* qA = pA + (size_t)(ic + 1) * 16 * FP;      // across compute)
      const __half2* qB = pB + (size_t)(ic + 1) * 16 * FP;
      va0 = *(const uint4*)qA;
      va1 = *(const uint4*)(qA + FP);
      vb0 = *(const uint4*)qB;
      vb1 = *(const uint4*)(qB + FP);
    }
    __syncthreads();
    // compute: per f-bin c: 2 A-frags (mt), 1 B-frag + rot16^sign variant
    #pragma unroll
    for (int c = 0; c < 4; ++c){
      const unsigned cb = (((unsigned)(c >> 1)) << 13);
      const unsigned cf = ((unsigned)(c & 1)) << 6;
      f16x8 af[2];
      #pragma unroll
      for (int mt = 0; mt < 2; ++mt){
        unsigned row = (unsigned)(wm*32 + mt*16 + l15);
        unsigned off = ((row << 7) + cf + ((unsigned)l4 << 4)) ^ ((row & 7) << 4);
        af[mt] = *(const f16x8*)(sb + cb + off);
      }
      unsigned orow = (unsigned)(wn*16 + l15);
      unsigned offb = ((orow << 7) + cf + ((unsigned)l4 << 4)) ^ ((orow & 7) << 4);
      f16x8 bf = *(const f16x8*)(sb + 16384 + cb + offb);
      union { f16x8 v; unsigned u[4]; } sB, dB;
      sB.v = bf;
      #pragma unroll
      for (int j = 0; j < 4; ++j)
        dB.u[j] = ((sB.u[j] >> 16) | (sB.u[j] << 16)) ^ 0x00008000u;  // (-wi, wr)
      #pragma unroll
      for (int mt = 0; mt < 2; ++mt){
        accR[mt][c] = __builtin_amdgcn_mfma_f32_16x16x32_f16(af[mt], bf,   accR[mt][c], 0, 0, 0);
        accI[mt][c] = __builtin_amdgcn_mfma_f32_16x16x32_f16(af[mt], dB.v, accI[mt][c], 0, 0, 0);
      }
    }
  }
  // epilogue: direct 16 B stores; lanes l15 -> 16 consecutive o = 256 B chunks
  const int olg = o0 + wn*16 + l15;
  #pragma unroll
  for (int mt = 0; mt < 2; ++mt)
    #pragma unroll
    for (int r = 0; r < 4; ++r){
      int bbl = bb0 + wm*32 + mt*16 + l4*4 + r;
      H2x4 hv;
      #pragma unroll
      for (int c = 0; c < 4; ++c) hv.h[c] = pack2(accR[mt][c][r], accI[mt][c][r]);
      *(H2x4*)(Yc + ((size_t)bbl * NFB + y) * OC * 4 + (size_t)olg * 4) = hv;
    }
}

// Y[bb,o,f] = sum_i X[bb,i,f]*conj(W[o,i,f]).  Tile: 8f x 16bb x TO o.
// grid = (BC/16, FP/8, OC/TO). Yc row = bb_local*OC + o_local (OLD layout).
// (VALU fallback for small-workspace chunk modes.)
template<int TO>
__global__ __launch_bounds__(THREADS) void keinsum(const __half2* __restrict__ Xc,
                                                   const __half2* __restrict__ Wc,
                                                   __half2* __restrict__ Yc, int OC){
  constexpr int OGN = TO/4;       // og groups
  constexpr int BB_PER = TO/8;    // bb per thread (bg groups = 128/TO)
  __shared__ float2 Xs[16*64];    // [bb][ii*8+f]
  __shared__ float2 Ws[TO*67];    // [o][ii*8+f], stride 67
  const int bb0 = blockIdx.x * 16;
  const int f0  = blockIdx.y * 8;
  const int o0  = blockIdx.z * TO;
  const int tid = threadIdx.x;
  const int f_id = tid & 7;
  const int g  = tid >> 3;
  const int og = g & (OGN - 1);
  const int bg = g / OGN;
  float2 acc[BB_PER][4];
  #pragma unroll
  for (int a_ = 0; a_ < BB_PER; ++a_)
    #pragma unroll
    for (int b_ = 0; b_ < 4; ++b_) acc[a_][b_] = f2(0.f, 0.f);

  for (int ic = 0; ic < 16; ++ic){
    __syncthreads();
    #pragma unroll
    for (int l = 0; l < TO/16; ++l){      // W chunk: TO*16 float4-sized pieces
      int u = l*THREADS + tid;
      int o = u >> 4, ii = (u >> 1) & 7, c = u & 1;
      H2x4 v = *(const H2x4*)(Wc + (size_t)((o0 + o)*128 + ic*8 + ii)*FP + f0 + c*4);
      #pragma unroll
      for (int j = 0; j < 4; ++j) Ws[o*67 + ii*8 + c*4 + j] = unpack2(v.h[j]);
    }
    {                                     // X chunk: 256 pieces, 1 iter
      int u = tid;
      int bbi = u >> 4, ii = (u >> 1) & 7, c = u & 1;
      H2x4 v = *(const H2x4*)(Xc + (size_t)((bb0 + bbi)*128 + ic*8 + ii)*FP + f0 + c*4);
      #pragma unroll
      for (int j = 0; j < 4; ++j) Xs[bbi*64 + ii*8 + c*4 + j] = unpack2(v.h[j]);
    }
    __syncthreads();
    #pragma unroll
    for (int ii = 0; ii < 8; ++ii){
      float2 xv[BB_PER], wv[4];
      #pragma unroll
      for (int bj = 0; bj < BB_PER; ++bj) xv[bj] = Xs[(bg*BB_PER + bj)*64 + ii*8 + f_id];
      #pragma unroll
      for (int oj = 0; oj < 4; ++oj) wv[oj] = Ws[(og*4 + oj)*67 + ii*8 + f_id];
      #pragma unroll
      for (int bj = 0; bj < BB_PER; ++bj)
        #pragma unroll
        for (int oj = 0; oj < 4; ++oj){
          acc[bj][oj].x += xv[bj].x*wv[oj].x + xv[bj].y*wv[oj].y;  // X*conj(W)
          acc[bj][oj].y += xv[bj].y*wv[oj].x - xv[bj].x*wv[oj].y;
        }
    }
  }
  #pragma unroll
  for (int bj = 0; bj < BB_PER; ++bj)
    #pragma unroll
    for (int oj = 0; oj < 4; ++oj){
      int row = (bb0 + bg*BB_PER + bj)*OC + (o0 + og*4 + oj);
      Yc[(size_t)row*FP + f0 + f_id] = pack2(acc[bj][oj].x, acc[bj][oj].y);
    }
}

// Inverse real FFT + scatter + bias. lr = bb_local*OC + o_local.
// newlay=1: Yc layout ((bbl*514 + fb)*OC + ol)*4 + c  (kceinsum path)
// newlay=0: Yc row-major lr*FP (fallback keinsum path)
__global__ __launch_bounds__(THREADS) void kifft(const __half2* __restrict__ Yc,
                                                 const float* __restrict__ bias,
                                                 float* __restrict__ out,
                                                 int bb_base, int o_base, int oc_shift,
                                                 int newlay){
  __shared__ float2 A[2048]; __shared__ float2 B[2048];
  __shared__ float XMs;
  int lr = blockIdx.x;
  int OCm = (1 << oc_shift) - 1;
  int bbl = lr >> oc_shift, ol = lr & OCm;
  int bb = bb_base + bbl;
  int o  = o_base + ol;
  int b = bb >> 2, blk = bb & 3;
  int tid = threadIdx.x;
  if (newlay){
    const size_t ustr = (size_t)(OCm + 1) * 4;            // half2 stride per f-block
    const __half2* Yb = Yc + (size_t)bbl * NFB * ustr + (size_t)ol * 4;
    #pragma unroll
    for (int l = 0; l < 2; ++l){
      int u = l*THREADS + tid;            // f-block u -> bins 4u..4u+3
      H2x4 v = *(const H2x4*)(Yb + (size_t)u * ustr);
      #pragma unroll
      for (int j = 0; j < 4; ++j) B[u*4 + j] = unpack2(v.h[j]);
    }
    if (tid == 0) XMs = __low2float(Yb[512 * ustr]);      // bin 2048
  } else {
    const __half2* Y = Yc + (size_t)lr * FP;
    #pragma unroll
    for (int l = 0; l < 2; ++l){
      int u = l*THREADS + tid;            // 4-bin piece
      H2x4 v = *(const H2x4*)(Y + u*4);
      #pragma unroll
      for (int j = 0; j < 4; ++j) B[u*4 + j] = unpack2(v.h[j]);
    }
    if (tid == 0) XMs = __low2float(Y[2048]);
  }
  __syncthreads();
  for (int k = tid; k < 2048; k += THREADS){   // rebuild packed spectrum Z
    float2 xk = B[k];
    float2 xm = (k == 0) ? f2(XMs, 0.f) : B[2048 - k];
    float ar = 0.5f*(xk.x + xm.x);
    float ai = 0.5f*(xk.y - xm.y);
    float dr = 0.5f*(xk.x - xm.x);
    float di = 0.5f*(xk.y + xm.y);
    float rev = (float)k * (1.0f/4096.0f);     // W_4096^{-k}
    float sw = __builtin_amdgcn_sinf(rev);
    float cw = __builtin_amdgcn_cosf(rev);
    float br = dr*cw - di*sw;
    float bi = dr*sw + di*cw;
    A[k] = f2(ar - bi, ai + br);               // Z = A + jB
  }
  float2* z = fft2048(A, B, tid, +1.0f);
  const float s = 1.0f/2048.0f;
  const float bv = bias[o];
  float* op = out + (size_t)(b*128 + o)*8193 + blk*2048;
  for (int n = tid; n < 2048; n += THREADS){
    if (n < 1024){
      op[2*n]     = z[n].x*s + bv;
      op[2*n + 1] = z[n].y*s + bv;
    } else if (n == 1024 && blk == 3){
      op[2048] = z[n].x*s + bv;                // final sample t = 8192
    }
  }
}

extern "C" void kernel_launch(void* const* d_in, const int* in_sizes, int n_in,
                              void* d_out, int out_size, void* d_ws, size_t ws_size,
                              hipStream_t stream){
  (void)in_sizes; (void)n_in; (void)out_size;
  const float* sig  = (const float*)d_in[0];
  const float* wgt  = (const float*)d_in[1];
  const float* bias = (const float*)d_in[2];
  float* out = (float*)d_out;
  const size_t rowb = (size_t)FP * sizeof(__half2);  // 8224 B per spectral row

  // Pick largest (OC, BC) chunking that fits ws_size.
  static const int modes[7][2] = {{128,128},{128,64},{128,32},{128,16},{64,16},{32,16},{16,16}};
  int OC = 0, BC = 0;
  for (int m = 0; m < 7; ++m){
    size_t need = ((size_t)modes[m][0]*128 + (size_t)modes[m][1]*128 +
                   (size_t)modes[m][1]*modes[m][0]) * rowb;
    if (need <= ws_size){ OC = modes[m][0]; BC = modes[m][1]; break; }
  }
  if (!OC) return;  // ws too small even for 35.8 MB plan — fail loudly via poison
  int ocs = 0; while ((1 << ocs) != OC) ++ocs;

  char* ws = (char*)d_ws;
  __half2* Wc = (__half2*)ws;
  __half2* Xc = (__half2*)(ws + (size_t)OC*128*rowb);
  __half2* Yc = (__half2*)(ws + ((size_t)OC*128 + (size_t)BC*128)*rowb);

  for (int ob = 0; ob < 128; ob += OC){
    hipLaunchKernelGGL(kfft_w, dim3(OC*128), dim3(THREADS), 0, stream, wgt, Wc, ob);
    for (int bbb = 0; bbb < 128; bbb += BC){
      hipLaunchKernelGGL(kfft_s, dim3(BC*128), dim3(THREADS), 0, stream, sig, Xc, bbb);
      int newlay = ((BC & 63) == 0 && (OC & 63) == 0) ? 1 : 0;
      if (newlay){
        int nbb = BC >> 6, no = OC >> 6;
        hipLaunchKernelGGL(kceinsum, dim3(nbb*no*NFB), dim3(CTHREADS), 0, stream,
                           Xc, Wc, Yc, nbb, OC);
      } else {
        dim3 ge(BC/16, FP/8, OC >= 64 ? OC/64 : 1);
        if (OC >= 64)
          hipLaunchKernelGGL(HIP_KERNEL_NAME(keinsum<64>), ge, dim3(THREADS), 0, stream, Xc, Wc, Yc, OC);
        else if (OC == 32)
          hipLaunchKernelGGL(HIP_KERNEL_NAME(keinsum<32>), ge, dim3(THREADS), 0, stream, Xc, Wc, Yc, OC);
        else
          hipLaunchKernelGGL(HIP_KERNEL_NAME(keinsum<16>), ge, dim3(THREADS), 0, stream, Xc, Wc, Yc, OC);
      }
      hipLaunchKernelGGL(kifft, dim3(BC*OC), dim3(THREADS), 0, stream, Yc, bias, out, bbb, ob, ocs, newlay);
    }
  }
}